// Round 7
// baseline (50.720 us; speedup 1.0000x reference)
//
#include <hip/hip_runtime.h>
#include <math.h>

// FocalCTCloss — MI355X (gfx950)
// T=160, N=128, C=6625, S=32, L=2S+1=65, blank=0
// R7: discriminating experiment — full-device gather (2640 blocks) into ws,
// then a slim per-sample scan kernel that stages from ws (MALL-hot after the
// kernel boundary) chunk-pipelined under the DPP-shift recursion.
//   A: gather_ws    2640 x 256  — one (n,t,j) element per thread, coalesced ws write
//   B: scan_kernel   128 x 1024 — stage chunk c+1 (float4) || scan chunk c
//   C: focal_reduce    1 x 128
// Tests per-CU-MSHR vs device-level random-line bound: CU-scaling => ~28us,
// device-bound => ~43us (then revert to R6 / declare roofline).

#define TT 160
#define NN 128
#define CC 6625
#define SS 32
#define JJ 33              // unique labels per (n,t): blank + 32
#define NTJ (TT * JJ)      // 5280 per sample
#define CHT 32             // t-steps per chunk
#define CHE (CHT * JJ)     // 1056 floats per chunk
#define CH4 (CHE / 4)      // 264 float4 per chunk
#define NCH 5
#define NEGV  (-1e30f)
#define LOG2E 1.4426950408889634f
#define LN2   0.6931471805599453f

// wave64 shift-up-by-1 via DPP: row_shr:1 + row_bcast15 patch for lanes 16k.
// Lane 0 result is garbage — callers mask explicitly.
__device__ __forceinline__ float dpp_up1(float x, bool row0lane) {
    int xi = __float_as_int(x);
    int shr = __builtin_amdgcn_update_dpp(xi, xi, 0x111, 0xf, 0xf, false); // row_shr:1
    int bc  = __builtin_amdgcn_update_dpp(xi, xi, 0x142, 0xf, 0xf, false); // row_bcast15
    return __int_as_float(row0lane ? bc : shr);
}

// ---------------- Kernel A: full-device gather ----------------
__global__ __launch_bounds__(256) void gather_ws_kernel(
    const float* __restrict__ log_probs,   // [T, N, C]
    const int*   __restrict__ targets,     // [N, S]
    float*       __restrict__ lp_ws)       // [N][NTJ], log2-scaled
{
    const int g = blockIdx.x * 256 + threadIdx.x;   // grid covers NN*NTJ exactly
    const int n = g / NTJ;
    const int r = g - n * NTJ;
    const int t = r / JJ;
    const int j = r - t * JJ;
    const int label = j ? targets[n * SS + j - 1] : 0;
    lp_ws[g] = log_probs[(size_t)t * (NN * CC) + (size_t)n * CC + label] * LOG2E;
}

// ---------------- Kernel B: stage-from-ws + DPP scan (pipelined) ----------------
__global__ __launch_bounds__(1024) void scan_kernel(
    const float* __restrict__ lp_ws,          // [N][NTJ]
    const int*   __restrict__ targets,        // [N, S]
    const int*   __restrict__ input_lengths,  // [N]
    const int*   __restrict__ target_lengths, // [N]
    float*       __restrict__ per_sample)     // [N]
{
    const int n   = blockIdx.x;
    const int tid = threadIdx.x;

    __shared__ float lp[NTJ];       // 21.1 KB
    __shared__ int   lab[JJ];

    if (tid < JJ) lab[tid] = (tid == 0) ? 0 : targets[n * SS + tid - 1];

    const float4* s4 = (const float4*)(lp_ws + (size_t)n * NTJ);
    float4* d4 = (float4*)lp;
    if (tid < CH4) d4[tid] = s4[tid];           // stage chunk 0
    __syncthreads();

    // ---- scan state (wave 0) ----
    const int lane = tid;
    const int tl = target_lengths[n];
    const int Lv = 2 * tl + 1;
    const int slot = (lane & 1) ? (1 + (lane >> 1)) : 0;
    const bool skip = (lane & 1) && (lane >= 3) &&
                      (lab[(lane & 63) >> 1 ? 1 + (lane >> 1) : 1] != lab[(lane >> 1) ? (lane >> 1) : 1]);
    const bool validl   = lane < Lv;
    const bool valid64  = 64 < Lv;
    const bool row0lane = (lane & 15) == 0;

    float v = NEGV;
    if (lane == 0) v = lp[0];                   // t=0, blank
    if (lane == 1) v = lp[1];                   // t=0, first label
    float e = NEGV;                             // l=64 rides on lane 63

    const int ilen = input_lengths[n];
    const int Tlim = (ilen < TT) ? ilen : TT;

    for (int c = 0; c < NCH; ++c) {
        // threads 64..64+263: stage chunk c+1 from ws (L2/MALL-hot)
        if (c + 1 < NCH) {
            const int r = tid - 64;
            if (r >= 0 && r < CH4) {
                const int i = (c + 1) * CH4 + r;
                d4[i] = s4[i];
            }
        }
        // wave 0: scan chunk c
        if (tid < 64) {
            const int t_lo = (c == 0) ? 1 : c * CHT;
            int t_hi = (c + 1) * CHT;
            if (t_hi > Tlim) t_hi = Tlim;
            for (int t = t_lo; t < t_hi; ++t) {
                const float u1 = dpp_up1(v, row0lane);   // v[lane-1]
                const float u2 = dpp_up1(u1, row0lane);  // v[lane-2]
                const float a2 = (lane == 0) ? NEGV : u1;
                const float a3 = skip ? u2 : NEGV;

                const float lpt64 = lp[t * JJ];          // blank slot, broadcast
                const float me = fmaxf(e, v);
                const float ne = me + log2f(exp2f(e - me) + exp2f(v - me)) + lpt64;

                const float m  = fmaxf(v, fmaxf(a2, a3));
                const float nv = m + log2f(exp2f(v - m) + exp2f(a2 - m) + exp2f(a3 - m))
                                   + lp[t * JJ + slot];

                v = validl  ? nv : NEGV;
                e = valid64 ? ne : NEGV;
            }
        }
        __syncthreads();
    }

    if (tid >= 64) return;

    const int i1 = 2 * tl;
    const int i2 = 2 * tl - 1;
    const float A1 = (i1 == 64) ? __shfl(e, 63) : __shfl(v, i1);
    const float A2 = __shfl(v, i2);
    if (lane == 0) {
        const float m = fmaxf(A1, A2);
        float loss = -LN2 * (m + log2f(exp2f(A1 - m) + exp2f(A2 - m)));
        if (loss > 1e29f) loss = 0.0f;           // zero_infinity
        per_sample[n] = loss / (float)tl;
    }
}

// ---------------- Kernel C: reduce + focal ----------------
__global__ __launch_bounds__(128) void focal_reduce_kernel(
    const float* __restrict__ per_sample, float* __restrict__ out)
{
    __shared__ float s[NN];
    int tid = threadIdx.x;
    s[tid] = per_sample[tid];
    __syncthreads();
    for (int off = NN / 2; off > 0; off >>= 1) {
        if (tid < off) s[tid] += s[tid + off];
        __syncthreads();
    }
    if (tid == 0) {
        float mean = s[0] / (float)NN;
        float pp = expf(-mean);
        float om = 1.0f - pp;
        out[0] = 0.5f * om * om * mean;          // ALPHA=0.5, GAMMA=2.0
    }
}

extern "C" void kernel_launch(void* const* d_in, const int* in_sizes, int n_in,
                              void* d_out, int out_size, void* d_ws, size_t ws_size,
                              hipStream_t stream) {
    const float* log_probs      = (const float*)d_in[0];
    const int*   targets        = (const int*)d_in[1];
    const int*   input_lengths  = (const int*)d_in[2];
    const int*   target_lengths = (const int*)d_in[3];
    float* out = (float*)d_out;

    float* per_sample = (float*)d_ws;                       // 128 floats
    float* lp_ws      = (float*)((char*)d_ws + 1024);       // NN*NTJ floats

    gather_ws_kernel<<<(NN * NTJ) / 256, 256, 0, stream>>>(log_probs, targets, lp_ws);
    scan_kernel<<<NN, 1024, 0, stream>>>(lp_ws, targets, input_lengths,
                                         target_lengths, per_sample);
    focal_reduce_kernel<<<1, NN, 0, stream>>>(per_sample, out);
}

// Round 10
// 46.616 us; speedup vs baseline: 1.0880x; 1.0880x over previous
//
#include <hip/hip_runtime.h>
#include <math.h>

// FocalCTCloss — MI355X (gfx950)
// T=160, N=128, C=6625, S=32, L=2S+1=65, blank=0
// R10: R6's passing fused kernel + single-kernel finalization, counter bug
// fixed. R8/R9 failed NOT on coherence: counter starts poisoned 0xAAAAAAAA
// ≡ 42 mod 128, so `old%128==127` fired at the 86th arrival — finalizer ran
// before ~42 blocks published (absmax ~ a few units, run-varying). Fix:
// hipMemsetAsync(counter,0,4,stream) before the kernel (allowed: not in the
// prohibited list, graph-capturable memset node) -> counter starts at 0
// every call, finalizer = true last arriver (old==127). Payload publish
// stays on RMWs (atomicExch release / atomicAdd(+0) acquire, agent scope).
// Fixed-order butterfly -> bit-deterministic output.
// Gather: device-level random-line bound (~676K lines, ~2.5 TB/s effective;
// 128 vs 256 gathering CUs made no difference, R6 vs R7). Scan hides under
// gather via the 5-chunk pipeline (waves 1..15 gather c+1, wave 0 scans c).

#define TT 160
#define NN 128
#define CC 6625
#define SS 32
#define JJ 33              // unique labels per (n,t): blank + 32
#define NTJ (TT * JJ)      // 5280
#define CHT 32             // t-steps per chunk
#define CHE (CHT * JJ)     // 1056 elements per chunk
#define NCH 5              // 160 / 32
#define NEGV  (-1e30f)
#define LOG2E 1.4426950408889634f
#define LN2   0.6931471805599453f

// wave64 shift-up-by-1 via DPP: row_shr:1 + row_bcast15 patch for lanes 16k.
// Lane 0 result is garbage — callers mask explicitly.
__device__ __forceinline__ float dpp_up1(float x, bool row0lane) {
    int xi = __float_as_int(x);
    int shr = __builtin_amdgcn_update_dpp(xi, xi, 0x111, 0xf, 0xf, false); // row_shr:1
    int bc  = __builtin_amdgcn_update_dpp(xi, xi, 0x142, 0xf, 0xf, false); // row_bcast15
    return __int_as_float(row0lane ? bc : shr);
}

__global__ __launch_bounds__(1024) void ctc_mega_kernel(
    const float* __restrict__ log_probs,      // [T, N, C]
    const int*   __restrict__ targets,        // [N, S]
    const int*   __restrict__ input_lengths,  // [N]
    const int*   __restrict__ target_lengths, // [N]
    unsigned int* __restrict__ counter,       // [1], memset to 0 pre-launch
    float*       __restrict__ per_sample,     // [N]
    float*       __restrict__ out)            // [1]
{
    const int n   = blockIdx.x;
    const int tid = threadIdx.x;

    __shared__ float lp[NTJ];       // 21.1 KB, log2-scaled unique columns
    __shared__ int   lab[JJ];       // slot 0 = blank, slot j = targets[j-1]

    if (tid < JJ) lab[tid] = (tid == 0) ? 0 : targets[n * SS + tid - 1];
    __syncthreads();

    const size_t rowbase = (size_t)n * CC;

    // ---- prologue: gather chunk 0 (t = 0..31), all 1024 threads ----
#pragma unroll
    for (int k = 0; k < 2; ++k) {
        const int i = tid + k * 1024;
        if (i < CHE) {
            const int t = i / JJ;
            const int j = i - t * JJ;
            lp[i] = log_probs[(size_t)t * (NN * CC) + rowbase + lab[j]] * LOG2E;
        }
    }
    __syncthreads();

    // ---- scan state (wave 0) ----
    const int lane = tid;                       // used only when tid < 64
    const int tl = target_lengths[n];
    const int Lv = 2 * tl + 1;
    const int slot = (lane & 1) ? (1 + (lane >> 1)) : 0;
    const bool skip = (lane & 1) && (lane >= 3) &&
                      (lab[1 + (lane >> 1)] != lab[lane >> 1]);
    const bool validl   = lane < Lv;
    const bool valid64  = 64 < Lv;
    const bool row0lane = (lane & 15) == 0;

    float v = NEGV;
    if (lane == 0) v = lp[0];                   // t=0, blank
    if (lane == 1) v = lp[1];                   // t=0, first label
    float e = NEGV;                             // l=64 rides on lane 63

    const int ilen = input_lengths[n];
    const int Tlim = (ilen < TT) ? ilen : TT;

    // ---- pipelined chunks: waves 1..15 gather c+1, wave 0 scans c ----
    for (int c = 0; c < NCH; ++c) {
        if (tid >= 64 && c + 1 < NCH) {
            const int base = (c + 1) * CHE;
#pragma unroll
            for (int k = 0; k < 2; ++k) {
                const int r = (tid - 64) + k * 960;
                if (r < CHE) {
                    const int i = base + r;
                    const int t = i / JJ;
                    const int j = i - t * JJ;
                    lp[i] = log_probs[(size_t)t * (NN * CC) + rowbase + lab[j]] * LOG2E;
                }
            }
        }
        if (tid < 64) {
            const int t_lo = (c == 0) ? 1 : c * CHT;
            int t_hi = (c + 1) * CHT;
            if (t_hi > Tlim) t_hi = Tlim;
            for (int t = t_lo; t < t_hi; ++t) {
                const float u1 = dpp_up1(v, row0lane);   // v[lane-1]
                const float u2 = dpp_up1(u1, row0lane);  // v[lane-2]
                const float a2 = (lane == 0) ? NEGV : u1;
                const float a3 = skip ? u2 : NEGV;

                const float lpt64 = lp[t * JJ];          // blank slot, broadcast
                const float me = fmaxf(e, v);
                const float ne = me + log2f(exp2f(e - me) + exp2f(v - me)) + lpt64;

                const float m  = fmaxf(v, fmaxf(a2, a3));
                const float nv = m + log2f(exp2f(v - m) + exp2f(a2 - m) + exp2f(a3 - m))
                                   + lp[t * JJ + slot];

                v = validl  ? nv : NEGV;
                e = valid64 ? ne : NEGV;
            }
        }
        __syncthreads();
    }

    if (tid >= 64) return;

    // ---- per-sample loss (lane 0) ----
    const int i1 = 2 * tl;
    const int i2 = 2 * tl - 1;
    const float A1 = (i1 == 64) ? __shfl(e, 63) : __shfl(v, i1);
    const float A2 = __shfl(v, i2);
    unsigned int old = 0;
    if (lane == 0) {
        const float m = fmaxf(A1, A2);
        float loss = -LN2 * (m + log2f(exp2f(A1 - m) + exp2f(A2 - m)));
        if (loss > 1e29f) loss = 0.0f;           // zero_infinity
        // publish payload as an RMW at the device coherence point
        (void)__hip_atomic_exchange(&per_sample[n], loss / (float)tl,
                                    __ATOMIC_RELEASE, __HIP_MEMORY_SCOPE_AGENT);
        old = __hip_atomic_fetch_add(counter, 1u,
                                     __ATOMIC_ACQ_REL, __HIP_MEMORY_SCOPE_AGENT);
    }
    old = __shfl((int)old, 0);

    // ---- true last arriver (counter memset to 0 pre-launch): reduce + focal ----
    if (old == 127u) {
        const float a = __hip_atomic_fetch_add(&per_sample[lane], 0.0f,
                                               __ATOMIC_ACQUIRE, __HIP_MEMORY_SCOPE_AGENT);
        const float b = __hip_atomic_fetch_add(&per_sample[lane + 64], 0.0f,
                                               __ATOMIC_ACQUIRE, __HIP_MEMORY_SCOPE_AGENT);
        float s = a + b;
        // deterministic butterfly (fixed pattern/order every call)
        for (int off = 32; off > 0; off >>= 1)
            s += __shfl_xor(s, off);
        if (lane == 0) {
            const float mean = s / (float)NN;
            const float pp = __expf(-mean);
            const float om = 1.0f - pp;
            out[0] = 0.5f * om * om * mean;      // ALPHA=0.5, GAMMA=2.0
        }
    }
}

extern "C" void kernel_launch(void* const* d_in, const int* in_sizes, int n_in,
                              void* d_out, int out_size, void* d_ws, size_t ws_size,
                              hipStream_t stream) {
    const float* log_probs      = (const float*)d_in[0];
    const int*   targets        = (const int*)d_in[1];
    const int*   input_lengths  = (const int*)d_in[2];
    const int*   target_lengths = (const int*)d_in[3];
    float* out = (float*)d_out;

    unsigned int* counter    = (unsigned int*)d_ws;           // 1 uint
    float*        per_sample = (float*)((char*)d_ws + 1024);  // 128 floats

    // Deterministic counter reset every call (graph-capturable memset node;
    // hipMemsetAsync is not in the prohibited list).
    hipMemsetAsync(counter, 0, sizeof(unsigned int), stream);

    ctc_mega_kernel<<<NN, 1024, 0, stream>>>(log_probs, targets, input_lengths,
                                             target_lengths, counter,
                                             per_sample, out);
}